// Round 14
// baseline (1412.389 us; speedup 1.0000x reference)
//
#include <hip/hip_runtime.h>
#include <hip/hip_bf16.h>

// Problem constants (fixed by reference)
#define T_STEPS 256
#define BATCH   16
#define HID     512
#define VOCAB   32000
#define M_TOT   (T_STEPS * BATCH)   // 4096
#define KT_DEC  16                  // 512/32
#define NT2     125                 // 32000/256
#define NTILES  (16 * NT2)          // 2000 dec tiles (256x256)
#define NSCAN   64                  // scan blocks (G=4 batches each)
#define GB      4                   // batches per scan block

typedef __attribute__((ext_vector_type(8))) short s8v;    // 8 bf16 (4 VGPRs)
typedef __attribute__((ext_vector_type(4))) float f4v;    // 4 f32 accum
typedef __attribute__((ext_vector_type(16))) float f16v;  // 16 f32 accum (32x32)
typedef unsigned short ushort_t;
typedef unsigned long long u64;

__device__ __forceinline__ unsigned short f2bf_rne(float f) {
  unsigned u = __float_as_uint(f);
  unsigned r = u + 0x7fffu + ((u >> 16) & 1u);
  return (unsigned short)(r >> 16);
}
__device__ __forceinline__ float bf2f(unsigned short s) {
  return __uint_as_float(((unsigned)s) << 16);
}
// Tile unit layout: tile = [128 rows r][4 k-groups kg] of s8v (16B) units.
__device__ __forceinline__ int unit_swz(int r, int kg) {
  return r * 4 + (kg ^ ((r >> 1) & 3));
}
// async global->LDS, 16B/lane; LDS dest = wave-uniform base + lane*16
__device__ __forceinline__ void gload16(const void* g, void* l) {
  __builtin_amdgcn_global_load_lds(
      (const __attribute__((address_space(1))) unsigned int*)g,
      (__attribute__((address_space(3))) unsigned int*)l, 16, 0, 0);
}
#define MFMA16(a, b, c) __builtin_amdgcn_mfma_f32_16x16x32_bf16((a), (b), (c), 0, 0, 0)
#define MFMA32(a, b, c) __builtin_amdgcn_mfma_f32_32x32x16_bf16((a), (b), (c), 0, 0, 0)
#define AGENT_LD(p) __hip_atomic_load((p), __ATOMIC_RELAXED, __HIP_MEMORY_SCOPE_AGENT)
#define AGENT_ST(p, v) __hip_atomic_store((p), (v), __ATOMIC_RELAXED, __HIP_MEMORY_SCOPE_AGENT)
#define SCHED0() __builtin_amdgcn_sched_barrier(0)

// ---------------------------------------------------------------------------
// K1 "head": blocks 0..127 = pre-GEMM; blocks 128..4127 = dec_w presplit.
// (unchanged from rounds 4-13)
// ---------------------------------------------------------------------------
__global__ __launch_bounds__(256, 2) void head_kernel(
    const int* __restrict__ tok, const float* __restrict__ emb,
    const float* __restrict__ w1, const float* __restrict__ b1f,
    float* __restrict__ pre,
    const float* __restrict__ dec_w, ushort_t* __restrict__ bhi,
    ushort_t* __restrict__ blo, int do_split) {
  if (blockIdx.x >= 128) {
    if (!do_split) return;
    const int pid = blockIdx.x - 128;
    const int nt = pid >> 4, ks = pid & 15;
    const int tid = threadIdx.x;
#pragma unroll
    for (int h = 0; h < 2; ++h) {
      int us = h * 256 + tid;
      int r = us >> 2, kg = us & 3;
      const float* src = dec_w + (size_t)(nt * 128 + r) * HID + ks * 32 + kg * 8;
      float4 v0 = *(const float4*)src;
      float4 v1 = *(const float4*)(src + 4);
      float av[8] = {v0.x, v0.y, v0.z, v0.w, v1.x, v1.y, v1.z, v1.w};
      s8v hi, lo;
#pragma unroll
      for (int j = 0; j < 8; ++j) {
        unsigned short hh = f2bf_rne(av[j]);
        hi[j] = (short)hh;
        lo[j] = (short)f2bf_rne(av[j] - bf2f(hh));
      }
      size_t base = ((size_t)(nt * 16 + ks) * 512 + unit_swz(r, kg)) * 8;
      *(s8v*)(bhi + base) = hi;
      *(s8v*)(blo + base) = lo;
    }
    return;
  }
  __shared__ s8v Ah[512], Al[512], Bh[512], Bl[512];
  const int mt = blockIdx.x & 31, nt = blockIdx.x >> 5;
  const int tid = threadIdx.x;
  const int lane = tid & 63, wave = tid >> 6;
  const int wm = wave >> 1, wn = wave & 1;
  const int m0 = mt * 128, n0 = nt * 128;
  f4v acc[4][4] = {};

  for (int ks = 0; ks < 16; ++ks) {
    const int k0 = ks * 32;
#pragma unroll
    for (int c = 0; c < 2; ++c) {
      int idx = c * 256 + tid;
      int r = idx >> 2, kg = idx & 3;
      int kgp = kg ^ (r & 3);
      int t_ = tok[m0 + r];
      const float* as = emb + (size_t)t_ * HID + k0 + kg * 8;
      float4 a0 = *(const float4*)as;
      float4 a1 = *(const float4*)(as + 4);
      float av[8] = {a0.x, a0.y, a0.z, a0.w, a1.x, a1.y, a1.z, a1.w};
      s8v ah, al;
#pragma unroll
      for (int j = 0; j < 8; ++j) {
        unsigned short h = f2bf_rne(av[j]);
        ah[j] = (short)h;
        al[j] = (short)f2bf_rne(av[j] - bf2f(h));
      }
      Ah[r * 4 + kgp] = ah;  Al[r * 4 + kgp] = al;
      const float* bs = w1 + (size_t)(n0 + r) * 1024 + k0 + kg * 8;
      float4 b0 = *(const float4*)bs;
      float4 b1v = *(const float4*)(bs + 4);
      float bv[8] = {b0.x, b0.y, b0.z, b0.w, b1v.x, b1v.y, b1v.z, b1v.w};
      s8v bh, bl;
#pragma unroll
      for (int j = 0; j < 8; ++j) {
        unsigned short h = f2bf_rne(bv[j]);
        bh[j] = (short)h;
        bl[j] = (short)f2bf_rne(bv[j] - bf2f(h));
      }
      Bh[r * 4 + kgp] = bh;  Bl[r * 4 + kgp] = bl;
    }
    __syncthreads();
    s8v afh[4], afl[4], bfh[4], bfl[4];
#pragma unroll
    for (int f = 0; f < 4; ++f) {
      int rA = wm * 64 + f * 16 + (lane & 15);
      afh[f] = Ah[rA * 4 + ((lane >> 4) ^ (rA & 3))];
      afl[f] = Al[rA * 4 + ((lane >> 4) ^ (rA & 3))];
      int rB = wn * 64 + f * 16 + (lane & 15);
      bfh[f] = Bh[rB * 4 + ((lane >> 4) ^ (rB & 3))];
      bfl[f] = Bl[rB * 4 + ((lane >> 4) ^ (rB & 3))];
    }
#pragma unroll
    for (int i = 0; i < 4; ++i)
#pragma unroll
      for (int j = 0; j < 4; ++j)
        acc[i][j] = MFMA16(afh[i], bfh[j], acc[i][j]);
#pragma unroll
    for (int i = 0; i < 4; ++i)
#pragma unroll
      for (int j = 0; j < 4; ++j)
        acc[i][j] = MFMA16(afl[i], bfh[j], acc[i][j]);
#pragma unroll
    for (int i = 0; i < 4; ++i)
#pragma unroll
      for (int j = 0; j < 4; ++j)
        acc[i][j] = MFMA16(afh[i], bfl[j], acc[i][j]);
    __syncthreads();
  }
#pragma unroll
  for (int j = 0; j < 4; ++j) {
    int col = n0 + wn * 64 + j * 16 + (lane & 15);
    float bias = b1f[col];
#pragma unroll
    for (int i = 0; i < 4; ++i)
#pragma unroll
      for (int rg = 0; rg < 4; ++rg) {
        int row = m0 + wm * 64 + i * 16 + (lane >> 4) * 4 + rg;
        pre[(size_t)row * HID + col] = acc[i][j][rg] + bias;
      }
  }
}

// ---------------------------------------------------------------------------
// K2 "scanodec" v2: 256 blocks x 512 thr x 128.25KB LDS -> 1 block/CU.
//   blocks 0..63  : scan role, G=4 batches/block (bq = blk&3, sg = blk>>2).
//                   Protocol identical to round 13 (proven): tagged-u64 h
//                   exchange, paired-u32 A-image AGENT stores, per-16-step
//                   slab release (target now 64). Then fall through to worker.
//   blocks 64..255: worker immediately (192 during scan, was 128).
// worker: byte-identical round-13 body (proven): acquire slab, gload16 A+B,
// counted vmcnt(8), MFMA clusters, NT stores, vmcnt(0) drain.
// ---------------------------------------------------------------------------
__global__ __launch_bounds__(512, 2) void scanodec_kernel(
    const float* __restrict__ w1, const float* __restrict__ pre,
    u64* hbuf, ushort_t* o_hi, ushort_t* o_lo, int* wq, int* scnt,
    const ushort_t* __restrict__ bhi, const ushort_t* __restrict__ blo,
    const float* __restrict__ dec_b, float* __restrict__ out,
    float* __restrict__ h_last_out, int ntiles) {
  extern __shared__ char LB[];   // 131328 B
  const int tid = threadIdx.x;

  if (blockIdx.x < NSCAN) {
    // ======================= scan role (G=4) =======================
    float* wLds  = (float*)LB;                   // 64 KiB swizzled wh slice
    float* hsb   = (float*)(LB + 65536);         // [4][512]
    float* partb = (float*)(LB + 65536 + 8192);  // [4][528]
    const int bq = blockIdx.x & 3;               // batch quad: b = bq*4 + k
    const int sg = blockIdx.x >> 2;              // row slice 0..15
    const int b0 = bq * GB;

#pragma unroll
    for (int k = 0; k < 8; ++k) {
      int uid = k * 512 + tid;
      int r = uid >> 7, u = uid & 127;
      float4 v = *(const float4*)(w1 + (size_t)(sg * 32 + r) * 1024 + 512 + u * 4);
      int dst = r * 512 + (u >> 3) * 32 + (((u & 7) ^ (r & 7)) << 2);
      *(float4*)(&wLds[dst]) = v;
    }
    __syncthreads();

    const int i = tid & 31, s = tid >> 5;
    const int rowbase = i * 512 + s * 32;
    const int isw = i & 7;
    unsigned* oh32 = (unsigned*)o_hi;
    unsigned* ol32 = (unsigned*)o_lo;

    for (int t = 0; t < T_STEPS; ++t) {
      const int cur = t & 1, nxt = cur ^ 1;

      float pv = 0.f;
      if (tid < 32 * GB) {
        int bl = tid >> 5, ii = tid & 31;
        pv = pre[(size_t)(t * BATCH + b0 + bl) * HID + sg * 32 + ii];
      }

      // poll 4 tags (thread owns element j=tid for each of the 4 batches)
      u64 e0, e1, e2, e3;
      {
        u64* p0 = hbuf + ((size_t)cur * BATCH + b0 + 0) * HID + tid;
        u64* p1 = hbuf + ((size_t)cur * BATCH + b0 + 1) * HID + tid;
        u64* p2 = hbuf + ((size_t)cur * BATCH + b0 + 2) * HID + tid;
        u64* p3 = hbuf + ((size_t)cur * BATCH + b0 + 3) * HID + tid;
        e0 = AGENT_LD(p0); e1 = AGENT_LD(p1);
        e2 = AGENT_LD(p2); e3 = AGENT_LD(p3);
        const unsigned tg = (unsigned)t;
        int spins = 0;
        while ((unsigned)(e0 >> 32) != tg || (unsigned)(e1 >> 32) != tg ||
               (unsigned)(e2 >> 32) != tg || (unsigned)(e3 >> 32) != tg) {
          __builtin_amdgcn_s_sleep(1);
          if ((unsigned)(e0 >> 32) != tg) e0 = AGENT_LD(p0);
          if ((unsigned)(e1 >> 32) != tg) e1 = AGENT_LD(p1);
          if ((unsigned)(e2 >> 32) != tg) e2 = AGENT_LD(p2);
          if ((unsigned)(e3 >> 32) != tg) e3 = AGENT_LD(p3);
          if (++spins > (1 << 21)) break;
        }
      }
      hsb[tid]        = __uint_as_float((unsigned)e0);
      hsb[512 + tid]  = __uint_as_float((unsigned)e1);
      hsb[1024 + tid] = __uint_as_float((unsigned)e2);
      hsb[1536 + tid] = __uint_as_float((unsigned)e3);
      __syncthreads();

      float a0 = 0.f, a1 = 0.f, a2 = 0.f, a3 = 0.f;
#pragma unroll
      for (int u = 0; u < 8; ++u) {
        float4 w = *(const float4*)(&wLds[rowbase + ((u ^ isw) << 2)]);
        float4 h0 = *(const float4*)(&hsb[s * 32 + (u << 2)]);
        float4 h1 = *(const float4*)(&hsb[512 + s * 32 + (u << 2)]);
        float4 h2 = *(const float4*)(&hsb[1024 + s * 32 + (u << 2)]);
        float4 h3 = *(const float4*)(&hsb[1536 + s * 32 + (u << 2)]);
        a0 += w.x * h0.x + w.y * h0.y + w.z * h0.z + w.w * h0.w;
        a1 += w.x * h1.x + w.y * h1.y + w.z * h1.z + w.w * h1.w;
        a2 += w.x * h2.x + w.y * h2.y + w.z * h2.z + w.w * h2.w;
        a3 += w.x * h3.x + w.y * h3.y + w.z * h3.z + w.w * h3.w;
      }
      partb[s * 33 + i]        = a0;
      partb[528 + s * 33 + i]  = a1;
      partb[1056 + s * 33 + i] = a2;
      partb[1584 + s * 33 + i] = a3;
      __syncthreads();

      if (tid < 32 * GB) {
        int bl = tid >> 5, ii = tid & 31;
        float ssum = 0.f;
#pragma unroll
        for (int ss = 0; ss < 16; ++ss) ssum += partb[bl * 528 + ss * 33 + ii];
        ssum += pv;
        float hn = tanhf(ssum);
        int b = b0 + bl;
        u64 ev = ((u64)(unsigned)(t + 1) << 32) | (u64)__float_as_uint(hn);
        AGENT_ST(hbuf + ((size_t)nxt * BATCH + b) * HID + sg * 32 + ii, ev);
        int m = t * BATCH + b;
        int mt = m >> 7, r = m & 127;
        int kg = ii >> 3, e = ii & 7;
        unsigned hi_u = f2bf_rne(hn);
        unsigned lo_u = f2bf_rne(hn - bf2f((unsigned short)hi_u));
        // pair adjacent e (even ii packs with ii+1; pairs stay in-wave)
        unsigned hi_n = __shfl_down(hi_u, 1);
        unsigned lo_n = __shfl_down(lo_u, 1);
        if ((ii & 1) == 0) {
          size_t u32i = ((size_t)(mt * 16 + sg) * 512 + unit_swz(r, kg)) * 4 + (e >> 1);
          AGENT_ST(oh32 + u32i, hi_u | (hi_n << 16));
          AGENT_ST(ol32 + u32i, lo_u | (lo_n << 16));
        }
        if (t == T_STEPS - 1) h_last_out[(size_t)b * HID + sg * 32 + ii] = hn;
      }
      if ((t & 15) == 15) {
        __syncthreads();   // all threads' slab stores ack'd
        if (tid == 0)
          __hip_atomic_fetch_add(scnt + (t >> 4) * 16, 1,
                                 __ATOMIC_RELEASE, __HIP_MEMORY_SCOPE_AGENT);
      }
    }
    __syncthreads();
    // fall through: become a worker
  }

  // ======================= dec worker (round-13 body, verbatim) ============
  {
    s8v* SB = (s8v*)LB;                 // 2 x 4096 units of 16B
    int* slot = (int*)(LB + 131072);
    const int lane = tid & 63, wv = tid >> 6;
    const int wm = wv >> 2, wn = wv & 3;
    const int lane32 = lane & 31, kh = lane >> 5;
    const int tB = wn >> 1;

    const ushort_t* gsrc;
    if (wv < 4) gsrc = (wv < 2) ? o_hi : o_lo;
    else        gsrc = (wv < 6) ? bhi : blo;

    int uB_[2][2], uA_[4][2];
#pragma unroll
    for (int tn = 0; tn < 2; ++tn)
#pragma unroll
      for (int s = 0; s < 2; ++s)
        uB_[tn][s] = (4 + tB) * 512 +
                     unit_swz((wn & 1) * 64 + tn * 32 + lane32, s * 2 + kh);
#pragma unroll
    for (int tm = 0; tm < 4; ++tm)
#pragma unroll
      for (int s = 0; s < 2; ++s)
        uA_[tm][s] = wm * 512 + unit_swz(tm * 32 + lane32, s * 2 + kh);

    for (;;) {
      if (tid == 0)
        *slot = __hip_atomic_fetch_add(wq, 1, __ATOMIC_RELAXED,
                                       __HIP_MEMORY_SCOPE_AGENT);
      __syncthreads();
      const int idx = *slot;
      if (idx >= ntiles) break;
      const int mt2 = idx / NT2, nt2 = idx % NT2;   // mt2-major: readiness order
      // ---- acquire: A-slab mt2 fully published by all 64 scan blocks ----
      if (tid == 0) {
        int spins = 0;
        while (__hip_atomic_load(scnt + mt2 * 16, __ATOMIC_ACQUIRE,
                                 __HIP_MEMORY_SCOPE_AGENT) < NSCAN) {
          __builtin_amdgcn_s_sleep(2);
          if (++spins > (1 << 22)) break;   // valve
        }
      }
      __syncthreads();

      const int gtile = ((wv < 4) ? mt2 * 2 : nt2 * 2) + (wv & 1);
      f16v acc[4][2] = {};

      // ---- prologue: stage kt=0 -> buf0, kt=1 -> buf1 ----
      {
        const char* g0 = (const char*)(gsrc + (size_t)(gtile * 16 + 0) * 4096);
        const char* g1 = (const char*)(gsrc + (size_t)(gtile * 16 + 1) * 4096);
        char* l0 = (char*)SB + wv * 8192;
        char* l1 = (char*)SB + 65536 + wv * 8192;
#pragma unroll
        for (int p = 0; p < 8; ++p) gload16(g0 + p * 1024 + (size_t)lane * 16, l0 + p * 1024);
#pragma unroll
        for (int p = 0; p < 8; ++p) gload16(g1 + p * 1024 + (size_t)lane * 16, l1 + p * 1024);
        asm volatile("s_waitcnt vmcnt(8)" ::: "memory");   // kt0 landed
        SCHED0();
        __builtin_amdgcn_s_barrier();
        SCHED0();
      }

      for (int kt = 0; kt < KT_DEC; ++kt) {
        const int c = kt & 1;
        const s8v* B0 = SB + c * 4096;

        s8v bh[2][2], bl[2][2], ah[4][2], al[4][2];
        // group 1: B (8) + A tm0/1 (8)
#pragma unroll
        for (int tn = 0; tn < 2; ++tn)
#pragma unroll
          for (int s = 0; s < 2; ++s) {
            bh[tn][s] = B0[uB_[tn][s]];
            bl[tn][s] = B0[1024 + uB_[tn][s]];
          }
#pragma unroll
        for (int tm = 0; tm < 2; ++tm)
#pragma unroll
          for (int s = 0; s < 2; ++s) {
            ah[tm][s] = B0[uA_[tm][s]];
            al[tm][s] = B0[1024 + uA_[tm][s]];
          }
        SCHED0();
        // group 2: A tm2/3 (8) — completes under cluster0
#pragma unroll
        for (int tm = 2; tm < 4; ++tm)
#pragma unroll
          for (int s = 0; s < 2; ++s) {
            ah[tm][s] = B0[uA_[tm][s]];
            al[tm][s] = B0[1024 + uA_[tm][s]];
          }
        asm volatile("s_waitcnt lgkmcnt(8)" ::: "memory");  // group1 ready
        SCHED0();

        __builtin_amdgcn_s_setprio(1);
        // cluster 0: tm0/1 (per-acc order: s0 hh, s1 hh, lh, lh, hl, hl)
#pragma unroll
        for (int s = 0; s < 2; ++s)
#pragma unroll
          for (int tn = 0; tn < 2; ++tn) {
            acc[0][tn] = MFMA32(ah[0][s], bh[tn][s], acc[0][tn]);
            acc[1][tn] = MFMA32(ah[1][s], bh[tn][s], acc[1][tn]);
          }
#pragma unroll
        for (int s = 0; s < 2; ++s)
#pragma unroll
          for (int tn = 0; tn < 2; ++tn) {
            acc[0][tn] = MFMA32(al[0][s], bh[tn][s], acc[0][tn]);
            acc[1][tn] = MFMA32(al[1][s], bh[tn][s], acc[1][tn]);
          }
#pragma unroll
        for (int s = 0; s < 2; ++s)
#pragma unroll
          for (int tn = 0; tn < 2; ++tn) {
            acc[0][tn] = MFMA32(ah[0][s], bl[tn][s], acc[0][tn]);
            acc[1][tn] = MFMA32(ah[1][s], bl[tn][s], acc[1][tn]);
          }
        __builtin_amdgcn_s_setprio(0);

        asm volatile("s_waitcnt lgkmcnt(0)" ::: "memory");  // all buf-c reads done
        SCHED0();
        __builtin_amdgcn_s_barrier();          // buf c free for overwrite
        SCHED0();
        if (kt + 2 < KT_DEC) {                 // stage kt+2 -> buf c
          const char* g = (const char*)(gsrc + (size_t)(gtile * 16 + kt + 2) * 4096);
          char* l = (char*)SB + c * 65536 + wv * 8192;
#pragma unroll
          for (int p = 0; p < 8; ++p) gload16(g + p * 1024 + (size_t)lane * 16, l + p * 1024);
        }
        SCHED0();

        __builtin_amdgcn_s_setprio(1);
        // cluster 1: tm2/3
#pragma unroll
        for (int s = 0; s < 2; ++s)
#pragma unroll
          for (int tn = 0; tn < 2; ++tn) {
            acc[2][tn] = MFMA32(ah[2][s], bh[tn][s], acc[2][tn]);
            acc[3][tn] = MFMA32(ah[3][s], bh[tn][s], acc[3][tn]);
          }
#pragma unroll
        for (int s = 0; s < 2; ++s)
#pragma unroll
          for (int tn = 0; tn < 2; ++tn) {
            acc[2][tn] = MFMA32(al[2][s], bh[tn][s], acc[2][tn]);
            acc[3][tn] = MFMA32(al[3][s], bh[tn][s], acc[3][tn]);
          }
#pragma unroll
        for (int s = 0; s < 2; ++s)
#pragma unroll
          for (int tn = 0; tn < 2; ++tn) {
            acc[2][tn] = MFMA32(ah[2][s], bl[tn][s], acc[2][tn]);
            acc[3][tn] = MFMA32(ah[3][s], bl[tn][s], acc[3][tn]);
          }
        __builtin_amdgcn_s_setprio(0);

        if (kt + 2 < KT_DEC) {
          asm volatile("s_waitcnt vmcnt(8)" ::: "memory");  // kt+1 landed
        } else {
          asm volatile("s_waitcnt vmcnt(0)" ::: "memory");  // tail drain
        }
        SCHED0();
        __builtin_amdgcn_s_barrier();          // kt+1 visible to all waves
        SCHED0();
      }

      // epilogue: NT stores, then drain so next tile's vmcnt accounting is exact
      const int m0 = mt2 * 256, n0 = nt2 * 256;
#pragma unroll
      for (int tn = 0; tn < 2; ++tn) {
        int col = n0 + wn * 64 + tn * 32 + lane32;
        float bias = dec_b[col];
#pragma unroll
        for (int tm = 0; tm < 4; ++tm) {
          int rowb = m0 + wm * 128 + tm * 32 + 4 * kh;
#pragma unroll
          for (int reg = 0; reg < 16; ++reg) {
            int row = rowb + (reg & 3) + 8 * (reg >> 2);
            __builtin_nontemporal_store(acc[tm][tn][reg] + bias,
                                        &out[(size_t)row * VOCAB + col]);
          }
        }
      }
      asm volatile("s_waitcnt vmcnt(0)" ::: "memory");
      SCHED0();
    }
  }
}

// ---------------------------------------------------------------------------
// Fallback dec (ws too small for presplit): unchanged round-13 fb.
// ---------------------------------------------------------------------------
__global__ __launch_bounds__(256, 2) void dec_gemm_fb(
    const ushort_t* __restrict__ o_hi, const ushort_t* __restrict__ o_lo,
    const float* __restrict__ dec_w, const float* __restrict__ dec_b,
    float* __restrict__ out) {
  __shared__ s8v Ah[512], Al[512], Bh[512], Bl[512];
  const int mt = blockIdx.x, nt = blockIdx.y;
  const int tid = threadIdx.x;
  const int lane = tid & 63, wave = tid >> 6;
  const int wm = wave >> 1, wn = wave & 1;
  const int kgl = lane >> 4, lr = lane & 15;
  const int m0 = mt * 128, n0 = nt * 128;
  f4v acc[4][4] = {};

  for (int ks = 0; ks < KT_DEC; ++ks) {
    const int k0 = ks * 32;
#pragma unroll
    for (int c = 0; c < 2; ++c) {
      int idx = c * 256 + tid;
      size_t abase = (size_t)(mt * 16 + ks) * 4096 + (size_t)idx * 8;
      Ah[idx] = *(const s8v*)(o_hi + abase);
      Al[idx] = *(const s8v*)(o_lo + abase);
      int r = idx >> 2, kg = idx & 3;
      const float* bs = dec_w + (size_t)(n0 + r) * HID + k0 + kg * 8;
      float4 b0 = *(const float4*)bs;
      float4 b1v = *(const float4*)(bs + 4);
      float bv[8] = {b0.x, b0.y, b0.z, b0.w, b1v.x, b1v.y, b1v.z, b1v.w};
      s8v bh, bl;
#pragma unroll
      for (int j = 0; j < 8; ++j) {
        unsigned short h = f2bf_rne(bv[j]);
        bh[j] = (short)h;
        bl[j] = (short)f2bf_rne(bv[j] - bf2f(h));
      }
      int ub = unit_swz(r, kg);
      Bh[ub] = bh;  Bl[ub] = bl;
    }
    __syncthreads();
    s8v afh[4], afl[4], bfh[4], bfl[4];
#pragma unroll
    for (int f = 0; f < 4; ++f) {
      int rA = wm * 64 + f * 16 + lr;
      int uA = unit_swz(rA, kgl);
      afh[f] = Ah[uA];  afl[f] = Al[uA];
      int rB = wn * 64 + f * 16 + lr;
      int uB = unit_swz(rB, kgl);
      bfh[f] = Bh[uB];  bfl[f] = Bl[uB];
    }
#pragma unroll
    for (int i = 0; i < 4; ++i)
#pragma unroll
      for (int j = 0; j < 4; ++j)
        acc[i][j] = MFMA16(afh[i], bfh[j], acc[i][j]);
#pragma unroll
    for (int i = 0; i < 4; ++i)
#pragma unroll
      for (int j = 0; j < 4; ++j)
        acc[i][j] = MFMA16(afl[i], bfh[j], acc[i][j]);
#pragma unroll
    for (int i = 0; i < 4; ++i)
#pragma unroll
      for (int j = 0; j < 4; ++j)
        acc[i][j] = MFMA16(afh[i], bfl[j], acc[i][j]);
    __syncthreads();
  }
#pragma unroll
  for (int j = 0; j < 4; ++j) {
    int col = n0 + wn * 64 + j * 16 + lr;
    float bias = dec_b[col];
#pragma unroll
    for (int i = 0; i < 4; ++i)
#pragma unroll
      for (int rg = 0; rg < 4; ++rg) {
        int row = m0 + wm * 64 + i * 16 + (lane >> 4) * 4 + rg;
        __builtin_nontemporal_store(acc[i][j][rg] + bias,
                                    &out[(size_t)row * VOCAB + col]);
      }
  }
}

// ---------------------------------------------------------------------------
// Workspace layout (bytes):
//   [0,       128 KiB)   hbuf: u64[2][16][512] (tag|f32)   (zeroed each call)
//   [131072]             wq: dec tile queue counter         (zeroed each call)
//   [131136, 132160)     scnt[16] slab counters, 64B apart  (zeroed each call)
//   [2 MiB,    6 MiB)    o_hi: tile-ready A hi images (32x16 tiles x 8 KiB)
//   [6 MiB,   10 MiB)    o_lo: tile-ready A lo images
//   [18 MiB,  26 MiB)    pre : 4096 x 512 f32
//   [26 MiB,  ~57.25M)   bhi : tile-ready dec_w hi
//   [58 MiB,  ~89.25M)   blo : tile-ready dec_w lo
// ---------------------------------------------------------------------------
extern "C" void kernel_launch(void* const* d_in, const int* in_sizes, int n_in,
                              void* d_out, int out_size, void* d_ws, size_t ws_size,
                              hipStream_t stream) {
  (void)in_sizes; (void)n_in; (void)out_size;
  const int*   tok   = (const int*)d_in[0];
  const float* emb   = (const float*)d_in[2];
  const float* w1    = (const float*)d_in[3];
  const float* b1    = (const float*)d_in[4];
  const float* dec_w = (const float*)d_in[5];
  const float* dec_b = (const float*)d_in[6];
  char* ws = (char*)d_ws;
  u64*      hbuf = (u64*)(ws);
  int*      wq   = (int*)(ws + 131072);
  int*      scnt = (int*)(ws + 131136);
  ushort_t* o_hi = (ushort_t*)(ws + (2u << 20));
  ushort_t* o_lo = (ushort_t*)(ws + (6u << 20));
  float*    pre  = (float*)(ws + (18u << 20));
  ushort_t* bhi  = (ushort_t*)(ws + (26u << 20));
  ushort_t* blo  = (ushort_t*)(ws + (58u << 20));
  float* out = (float*)d_out;

  const int big = (ws_size >= (size_t)92 * 1024 * 1024) ? 1 : 0;

  hipMemsetAsync(ws, 0, 132160, stream);   // hbuf + wq + scnt
  head_kernel<<<dim3(4128), dim3(256), 0, stream>>>(
      tok, emb, w1, b1, pre, dec_w, bhi, blo, big);
  hipFuncSetAttribute((const void*)scanodec_kernel,
                      hipFuncAttributeMaxDynamicSharedMemorySize, 131328);
  scanodec_kernel<<<dim3(256), dim3(512), 131328, stream>>>(
      w1, pre, hbuf, o_hi, o_lo, wq, scnt, bhi, blo, dec_b, out,
      out + (size_t)M_TOT * VOCAB, big ? NTILES : 0);
  if (!big)
    dec_gemm_fb<<<dim3(32, 250), dim3(256), 0, stream>>>(o_hi, o_lo, dec_w, dec_b, out);
}

// Round 15
// 678.512 us; speedup vs baseline: 2.0816x; 2.0816x over previous
//
#include <hip/hip_runtime.h>
#include <hip/hip_bf16.h>

// Problem constants (fixed by reference)
#define T_STEPS 256
#define BATCH   16
#define HID     512
#define VOCAB   32000
#define M_TOT   (T_STEPS * BATCH)   // 4096
#define KT_DEC  16                  // 512/32
#define NT2     125                 // 32000/256
#define NTILES  (16 * NT2)          // 2000 dec tiles (256x256)

typedef __attribute__((ext_vector_type(8))) short s8v;    // 8 bf16 (4 VGPRs)
typedef __attribute__((ext_vector_type(4))) float f4v;    // 4 f32 accum
typedef __attribute__((ext_vector_type(16))) float f16v;  // 16 f32 accum (32x32)
typedef unsigned short ushort_t;
typedef unsigned long long u64;

__device__ __forceinline__ unsigned short f2bf_rne(float f) {
  unsigned u = __float_as_uint(f);
  unsigned r = u + 0x7fffu + ((u >> 16) & 1u);
  return (unsigned short)(r >> 16);
}
__device__ __forceinline__ float bf2f(unsigned short s) {
  return __uint_as_float(((unsigned)s) << 16);
}
// Tile unit layout: tile = [128 rows r][4 k-groups kg] of s8v (16B) units.
__device__ __forceinline__ int unit_swz(int r, int kg) {
  return r * 4 + (kg ^ ((r >> 1) & 3));
}
// async global->LDS, 16B/lane; LDS dest = wave-uniform base + lane*16
__device__ __forceinline__ void gload16(const void* g, void* l) {
  __builtin_amdgcn_global_load_lds(
      (const __attribute__((address_space(1))) unsigned int*)g,
      (__attribute__((address_space(3))) unsigned int*)l, 16, 0, 0);
}
#define MFMA16(a, b, c) __builtin_amdgcn_mfma_f32_16x16x32_bf16((a), (b), (c), 0, 0, 0)
#define MFMA32(a, b, c) __builtin_amdgcn_mfma_f32_32x32x16_bf16((a), (b), (c), 0, 0, 0)
#define AGENT_LD(p) __hip_atomic_load((p), __ATOMIC_RELAXED, __HIP_MEMORY_SCOPE_AGENT)
#define AGENT_ST(p, v) __hip_atomic_store((p), (v), __ATOMIC_RELAXED, __HIP_MEMORY_SCOPE_AGENT)
#define SCHED0() __builtin_amdgcn_sched_barrier(0)

// ---------------------------------------------------------------------------
// K1 "head": blocks 0..127 = pre-GEMM; blocks 128..4127 = dec_w presplit.
// ---------------------------------------------------------------------------
__global__ __launch_bounds__(256, 2) void head_kernel(
    const int* __restrict__ tok, const float* __restrict__ emb,
    const float* __restrict__ w1, const float* __restrict__ b1f,
    float* __restrict__ pre,
    const float* __restrict__ dec_w, ushort_t* __restrict__ bhi,
    ushort_t* __restrict__ blo, int do_split) {
  if (blockIdx.x >= 128) {
    if (!do_split) return;
    const int pid = blockIdx.x - 128;
    const int nt = pid >> 4, ks = pid & 15;
    const int tid = threadIdx.x;
#pragma unroll
    for (int h = 0; h < 2; ++h) {
      int us = h * 256 + tid;
      int r = us >> 2, kg = us & 3;
      const float* src = dec_w + (size_t)(nt * 128 + r) * HID + ks * 32 + kg * 8;
      float4 v0 = *(const float4*)src;
      float4 v1 = *(const float4*)(src + 4);
      float av[8] = {v0.x, v0.y, v0.z, v0.w, v1.x, v1.y, v1.z, v1.w};
      s8v hi, lo;
#pragma unroll
      for (int j = 0; j < 8; ++j) {
        unsigned short hh = f2bf_rne(av[j]);
        hi[j] = (short)hh;
        lo[j] = (short)f2bf_rne(av[j] - bf2f(hh));
      }
      size_t base = ((size_t)(nt * 16 + ks) * 512 + unit_swz(r, kg)) * 8;
      *(s8v*)(bhi + base) = hi;
      *(s8v*)(blo + base) = lo;
    }
    return;
  }
  __shared__ s8v Ah[512], Al[512], Bh[512], Bl[512];
  const int mt = blockIdx.x & 31, nt = blockIdx.x >> 5;
  const int tid = threadIdx.x;
  const int lane = tid & 63, wave = tid >> 6;
  const int wm = wave >> 1, wn = wave & 1;
  const int m0 = mt * 128, n0 = nt * 128;
  f4v acc[4][4] = {};

  for (int ks = 0; ks < 16; ++ks) {
    const int k0 = ks * 32;
#pragma unroll
    for (int c = 0; c < 2; ++c) {
      int idx = c * 256 + tid;
      int r = idx >> 2, kg = idx & 3;
      int kgp = kg ^ (r & 3);
      int t_ = tok[m0 + r];
      const float* as = emb + (size_t)t_ * HID + k0 + kg * 8;
      float4 a0 = *(const float4*)as;
      float4 a1 = *(const float4*)(as + 4);
      float av[8] = {a0.x, a0.y, a0.z, a0.w, a1.x, a1.y, a1.z, a1.w};
      s8v ah, al;
#pragma unroll
      for (int j = 0; j < 8; ++j) {
        unsigned short h = f2bf_rne(av[j]);
        ah[j] = (short)h;
        al[j] = (short)f2bf_rne(av[j] - bf2f(h));
      }
      Ah[r * 4 + kgp] = ah;  Al[r * 4 + kgp] = al;
      const float* bs = w1 + (size_t)(n0 + r) * 1024 + k0 + kg * 8;
      float4 b0 = *(const float4*)bs;
      float4 b1v = *(const float4*)(bs + 4);
      float bv[8] = {b0.x, b0.y, b0.z, b0.w, b1v.x, b1v.y, b1v.z, b1v.w};
      s8v bh, bl;
#pragma unroll
      for (int j = 0; j < 8; ++j) {
        unsigned short h = f2bf_rne(bv[j]);
        bh[j] = (short)h;
        bl[j] = (short)f2bf_rne(bv[j] - bf2f(h));
      }
      Bh[r * 4 + kgp] = bh;  Bl[r * 4 + kgp] = bl;
    }
    __syncthreads();
    s8v afh[4], afl[4], bfh[4], bfl[4];
#pragma unroll
    for (int f = 0; f < 4; ++f) {
      int rA = wm * 64 + f * 16 + (lane & 15);
      afh[f] = Ah[rA * 4 + ((lane >> 4) ^ (rA & 3))];
      afl[f] = Al[rA * 4 + ((lane >> 4) ^ (rA & 3))];
      int rB = wn * 64 + f * 16 + (lane & 15);
      bfh[f] = Bh[rB * 4 + ((lane >> 4) ^ (rB & 3))];
      bfl[f] = Bl[rB * 4 + ((lane >> 4) ^ (rB & 3))];
    }
#pragma unroll
    for (int i = 0; i < 4; ++i)
#pragma unroll
      for (int j = 0; j < 4; ++j)
        acc[i][j] = MFMA16(afh[i], bfh[j], acc[i][j]);
#pragma unroll
    for (int i = 0; i < 4; ++i)
#pragma unroll
      for (int j = 0; j < 4; ++j)
        acc[i][j] = MFMA16(afl[i], bfh[j], acc[i][j]);
#pragma unroll
    for (int i = 0; i < 4; ++i)
#pragma unroll
      for (int j = 0; j < 4; ++j)
        acc[i][j] = MFMA16(afh[i], bfl[j], acc[i][j]);
    __syncthreads();
  }
#pragma unroll
  for (int j = 0; j < 4; ++j) {
    int col = n0 + wn * 64 + j * 16 + (lane & 15);
    float bias = b1f[col];
#pragma unroll
    for (int i = 0; i < 4; ++i)
#pragma unroll
      for (int rg = 0; rg < 4; ++rg) {
        int row = m0 + wm * 64 + i * 16 + (lane >> 4) * 4 + rg;
        pre[(size_t)row * HID + col] = acc[i][j][rg] + bias;
      }
  }
}

// ---------------------------------------------------------------------------
// K2 "scanodec" (round-13 proven config, G=2):
//   blocks 0..127 : scan role (2 batches/block); tagged-u64 h exchange;
//                   paired-u32 A-image AGENT stores; per-16-step slab
//                   release (target 128). Then fall through to worker.
//   blocks 128..255: worker immediately.
// worker: acquire slab, gload16 A+B, counted vmcnt(8), MFMA clusters,
// NT stores, vmcnt(0) drain.
// ---------------------------------------------------------------------------
__global__ __launch_bounds__(512, 2) void scanodec_kernel(
    const float* __restrict__ w1, const float* __restrict__ pre,
    u64* hbuf, ushort_t* o_hi, ushort_t* o_lo, int* wq, int* scnt,
    const ushort_t* __restrict__ bhi, const ushort_t* __restrict__ blo,
    const float* __restrict__ dec_b, float* __restrict__ out,
    float* __restrict__ h_last_out, int ntiles) {
  extern __shared__ char LB[];   // 131328 B
  const int tid = threadIdx.x;

  if (blockIdx.x < 128) {
    // ======================= scan role (round-9 core) =======================
    float* wLds  = (float*)LB;                   // 64 KiB swizzled wh slice
    float* hsb   = (float*)(LB + 65536);         // [2][512]
    float* partb = (float*)(LB + 69632);         // [2][528]
    const int bp = blockIdx.x & 7;
    const int sg = blockIdx.x >> 3;
    const int b0 = bp * 2, b1i = b0 + 1;

#pragma unroll
    for (int k = 0; k < 8; ++k) {
      int uid = k * 512 + tid;
      int r = uid >> 7, u = uid & 127;
      float4 v = *(const float4*)(w1 + (size_t)(sg * 32 + r) * 1024 + 512 + u * 4);
      int dst = r * 512 + (u >> 3) * 32 + (((u & 7) ^ (r & 7)) << 2);
      *(float4*)(&wLds[dst]) = v;
    }
    __syncthreads();

    const int i = tid & 31, s = tid >> 5;
    const int rowbase = i * 512 + s * 32;
    const int isw = i & 7;
    unsigned* oh32 = (unsigned*)o_hi;
    unsigned* ol32 = (unsigned*)o_lo;

    for (int t = 0; t < T_STEPS; ++t) {
      const int cur = t & 1, nxt = cur ^ 1;

      float pv = 0.f;
      if (tid < 64) {
        int bl = tid >> 5, ii = tid & 31;
        pv = pre[(size_t)(t * BATCH + b0 + bl) * HID + sg * 32 + ii];
      }

      u64* p0 = hbuf + ((size_t)cur * BATCH + b0) * HID + tid;
      u64* p1 = hbuf + ((size_t)cur * BATCH + b1i) * HID + tid;
      u64 e0 = AGENT_LD(p0);
      u64 e1 = AGENT_LD(p1);
      int spins = 0;
      while ((unsigned)(e0 >> 32) != (unsigned)t || (unsigned)(e1 >> 32) != (unsigned)t) {
        __builtin_amdgcn_s_sleep(1);
        if ((unsigned)(e0 >> 32) != (unsigned)t) e0 = AGENT_LD(p0);
        if ((unsigned)(e1 >> 32) != (unsigned)t) e1 = AGENT_LD(p1);
        if (++spins > (1 << 21)) break;
      }
      hsb[tid] = __uint_as_float((unsigned)e0);
      hsb[512 + tid] = __uint_as_float((unsigned)e1);
      __syncthreads();

      float a0 = 0.f, a1 = 0.f;
#pragma unroll
      for (int u = 0; u < 8; ++u) {
        float4 w = *(const float4*)(&wLds[rowbase + ((u ^ isw) << 2)]);
        float4 h0 = *(const float4*)(&hsb[s * 32 + (u << 2)]);
        float4 h1 = *(const float4*)(&hsb[512 + s * 32 + (u << 2)]);
        a0 += w.x * h0.x + w.y * h0.y + w.z * h0.z + w.w * h0.w;
        a1 += w.x * h1.x + w.y * h1.y + w.z * h1.z + w.w * h1.w;
      }
      partb[s * 33 + i] = a0;
      partb[528 + s * 33 + i] = a1;
      __syncthreads();

      if (tid < 64) {
        int bl = tid >> 5, ii = tid & 31;
        float ssum = 0.f;
#pragma unroll
        for (int ss = 0; ss < 16; ++ss) ssum += partb[bl * 528 + ss * 33 + ii];
        ssum += pv;
        float hn = tanhf(ssum);
        int b = b0 + bl;
        u64 ev = ((u64)(unsigned)(t + 1) << 32) | (u64)__float_as_uint(hn);
        AGENT_ST(hbuf + ((size_t)nxt * BATCH + b) * HID + sg * 32 + ii, ev);
        int m = t * BATCH + b;
        int mt = m >> 7, r = m & 127;
        int kg = ii >> 3, e = ii & 7;
        unsigned hi_u = f2bf_rne(hn);
        unsigned lo_u = f2bf_rne(hn - bf2f((unsigned short)hi_u));
        // pair adjacent e (even ii packs with ii+1) -> one u32 per image
        unsigned hi_n = __shfl_down(hi_u, 1);
        unsigned lo_n = __shfl_down(lo_u, 1);
        if ((ii & 1) == 0) {
          size_t u32i = ((size_t)(mt * 16 + sg) * 512 + unit_swz(r, kg)) * 4 + (e >> 1);
          AGENT_ST(oh32 + u32i, hi_u | (hi_n << 16));
          AGENT_ST(ol32 + u32i, lo_u | (lo_n << 16));
        }
        if (t == T_STEPS - 1) h_last_out[(size_t)b * HID + sg * 32 + ii] = hn;
      }
      if ((t & 15) == 15) {
        __syncthreads();   // all threads' slab stores ack'd (implicit waitcnt)
        if (tid == 0)
          __hip_atomic_fetch_add(scnt + (t >> 4) * 16, 1,
                                 __ATOMIC_RELEASE, __HIP_MEMORY_SCOPE_AGENT);
      }
    }
    __syncthreads();
    // fall through: become a worker
  }

  // ======================= dec worker (round-9 body) =======================
  {
    s8v* SB = (s8v*)LB;                 // 2 x 4096 units of 16B
    int* slot = (int*)(LB + 131072);
    const int lane = tid & 63, wv = tid >> 6;
    const int wm = wv >> 2, wn = wv & 3;
    const int lane32 = lane & 31, kh = lane >> 5;
    const int tB = wn >> 1;

    const ushort_t* gsrc;
    if (wv < 4) gsrc = (wv < 2) ? o_hi : o_lo;
    else        gsrc = (wv < 6) ? bhi : blo;

    // precomputed LDS unit indices (constant across kt; lo image = +1024)
    int uB_[2][2], uA_[4][2];
#pragma unroll
    for (int tn = 0; tn < 2; ++tn)
#pragma unroll
      for (int s = 0; s < 2; ++s)
        uB_[tn][s] = (4 + tB) * 512 +
                     unit_swz((wn & 1) * 64 + tn * 32 + lane32, s * 2 + kh);
#pragma unroll
    for (int tm = 0; tm < 4; ++tm)
#pragma unroll
      for (int s = 0; s < 2; ++s)
        uA_[tm][s] = wm * 512 + unit_swz(tm * 32 + lane32, s * 2 + kh);

    for (;;) {
      if (tid == 0)
        *slot = __hip_atomic_fetch_add(wq, 1, __ATOMIC_RELAXED,
                                       __HIP_MEMORY_SCOPE_AGENT);
      __syncthreads();
      const int idx = *slot;
      if (idx >= ntiles) break;
      const int mt2 = idx / NT2, nt2 = idx % NT2;   // mt2-major: readiness order
      // ---- acquire: A-slab mt2 fully published by all 128 scan blocks ----
      if (tid == 0) {
        int spins = 0;
        while (__hip_atomic_load(scnt + mt2 * 16, __ATOMIC_ACQUIRE,
                                 __HIP_MEMORY_SCOPE_AGENT) < 128) {
          __builtin_amdgcn_s_sleep(2);
          if (++spins > (1 << 22)) break;   // valve
        }
      }
      __syncthreads();

      const int gtile = ((wv < 4) ? mt2 * 2 : nt2 * 2) + (wv & 1);
      f16v acc[4][2] = {};

      // ---- prologue: stage kt=0 -> buf0, kt=1 -> buf1 ----
      {
        const char* g0 = (const char*)(gsrc + (size_t)(gtile * 16 + 0) * 4096);
        const char* g1 = (const char*)(gsrc + (size_t)(gtile * 16 + 1) * 4096);
        char* l0 = (char*)SB + wv * 8192;
        char* l1 = (char*)SB + 65536 + wv * 8192;
#pragma unroll
        for (int p = 0; p < 8; ++p) gload16(g0 + p * 1024 + (size_t)lane * 16, l0 + p * 1024);
#pragma unroll
        for (int p = 0; p < 8; ++p) gload16(g1 + p * 1024 + (size_t)lane * 16, l1 + p * 1024);
        asm volatile("s_waitcnt vmcnt(8)" ::: "memory");   // kt0 landed
        SCHED0();
        __builtin_amdgcn_s_barrier();
        SCHED0();
      }

      for (int kt = 0; kt < KT_DEC; ++kt) {
        const int c = kt & 1;
        const s8v* B0 = SB + c * 4096;

        s8v bh[2][2], bl[2][2], ah[4][2], al[4][2];
        // group 1: B (8) + A tm0/1 (8)
#pragma unroll
        for (int tn = 0; tn < 2; ++tn)
#pragma unroll
          for (int s = 0; s < 2; ++s) {
            bh[tn][s] = B0[uB_[tn][s]];
            bl[tn][s] = B0[1024 + uB_[tn][s]];
          }
#pragma unroll
        for (int tm = 0; tm < 2; ++tm)
#pragma unroll
          for (int s = 0; s < 2; ++s) {
            ah[tm][s] = B0[uA_[tm][s]];
            al[tm][s] = B0[1024 + uA_[tm][s]];
          }
        SCHED0();
        // group 2: A tm2/3 (8) — completes under cluster0
#pragma unroll
        for (int tm = 2; tm < 4; ++tm)
#pragma unroll
          for (int s = 0; s < 2; ++s) {
            ah[tm][s] = B0[uA_[tm][s]];
            al[tm][s] = B0[1024 + uA_[tm][s]];
          }
        asm volatile("s_waitcnt lgkmcnt(8)" ::: "memory");  // group1 ready
        SCHED0();

        __builtin_amdgcn_s_setprio(1);
        // cluster 0: tm0/1 (per-acc order: s0 hh, s1 hh, lh, lh, hl, hl)
#pragma unroll
        for (int s = 0; s < 2; ++s)
#pragma unroll
          for (int tn = 0; tn < 2; ++tn) {
            acc[0][tn] = MFMA32(ah[0][s], bh[tn][s], acc[0][tn]);
            acc[1][tn] = MFMA32(ah[1][s], bh[tn][s], acc[1][tn]);
          }
#pragma unroll
        for (int s = 0; s < 2; ++s)
#pragma unroll
          for (int tn = 0; tn < 2; ++tn) {
            acc[0][tn] = MFMA32(al[0][s], bh[tn][s], acc[0][tn]);
            acc[1][tn] = MFMA32(al[1][s], bh[tn][s], acc[1][tn]);
          }
#pragma unroll
        for (int s = 0; s < 2; ++s)
#pragma unroll
          for (int tn = 0; tn < 2; ++tn) {
            acc[0][tn] = MFMA32(ah[0][s], bl[tn][s], acc[0][tn]);
            acc[1][tn] = MFMA32(ah[1][s], bl[tn][s], acc[1][tn]);
          }
        __builtin_amdgcn_s_setprio(0);

        asm volatile("s_waitcnt lgkmcnt(0)" ::: "memory");  // all buf-c reads done
        SCHED0();
        __builtin_amdgcn_s_barrier();          // buf c free for overwrite
        SCHED0();
        if (kt + 2 < KT_DEC) {                 // stage kt+2 -> buf c
          const char* g = (const char*)(gsrc + (size_t)(gtile * 16 + kt + 2) * 4096);
          char* l = (char*)SB + c * 65536 + wv * 8192;
#pragma unroll
          for (int p = 0; p < 8; ++p) gload16(g + p * 1024 + (size_t)lane * 16, l + p * 1024);
        }
        SCHED0();

        __builtin_amdgcn_s_setprio(1);
        // cluster 1: tm2/3
#pragma unroll
        for (int s = 0; s < 2; ++s)
#pragma unroll
          for (int tn = 0; tn < 2; ++tn) {
            acc[2][tn] = MFMA32(ah[2][s], bh[tn][s], acc[2][tn]);
            acc[3][tn] = MFMA32(ah[3][s], bh[tn][s], acc[3][tn]);
          }
#pragma unroll
        for (int s = 0; s < 2; ++s)
#pragma unroll
          for (int tn = 0; tn < 2; ++tn) {
            acc[2][tn] = MFMA32(al[2][s], bh[tn][s], acc[2][tn]);
            acc[3][tn] = MFMA32(al[3][s], bh[tn][s], acc[3][tn]);
          }
#pragma unroll
        for (int s = 0; s < 2; ++s)
#pragma unroll
          for (int tn = 0; tn < 2; ++tn) {
            acc[2][tn] = MFMA32(ah[2][s], bl[tn][s], acc[2][tn]);
            acc[3][tn] = MFMA32(ah[3][s], bl[tn][s], acc[3][tn]);
          }
        __builtin_amdgcn_s_setprio(0);

        if (kt + 2 < KT_DEC) {
          asm volatile("s_waitcnt vmcnt(8)" ::: "memory");  // kt+1 landed
        } else {
          asm volatile("s_waitcnt vmcnt(0)" ::: "memory");  // tail drain
        }
        SCHED0();
        __builtin_amdgcn_s_barrier();          // kt+1 visible to all waves
        SCHED0();
      }

      // epilogue: NT stores, then drain so next tile's vmcnt accounting is exact
      const int m0 = mt2 * 256, n0 = nt2 * 256;
#pragma unroll
      for (int tn = 0; tn < 2; ++tn) {
        int col = n0 + wn * 64 + tn * 32 + lane32;
        float bias = dec_b[col];
#pragma unroll
        for (int tm = 0; tm < 4; ++tm) {
          int rowb = m0 + wm * 128 + tm * 32 + 4 * kh;
#pragma unroll
          for (int reg = 0; reg < 16; ++reg) {
            int row = rowb + (reg & 3) + 8 * (reg >> 2);
            __builtin_nontemporal_store(acc[tm][tn][reg] + bias,
                                        &out[(size_t)row * VOCAB + col]);
          }
        }
      }
      asm volatile("s_waitcnt vmcnt(0)" ::: "memory");
      SCHED0();
    }
  }
}

// ---------------------------------------------------------------------------
// Fallback dec (ws too small for presplit): A from o_hi/o_lo images
// (cross-dispatch, plain), B split on the fly. 128x128 tiles.
// ---------------------------------------------------------------------------
__global__ __launch_bounds__(256, 2) void dec_gemm_fb(
    const ushort_t* __restrict__ o_hi, const ushort_t* __restrict__ o_lo,
    const float* __restrict__ dec_w, const float* __restrict__ dec_b,
    float* __restrict__ out) {
  __shared__ s8v Ah[512], Al[512], Bh[512], Bl[512];
  const int mt = blockIdx.x, nt = blockIdx.y;
  const int tid = threadIdx.x;
  const int lane = tid & 63, wave = tid >> 6;
  const int wm = wave >> 1, wn = wave & 1;
  const int kgl = lane >> 4, lr = lane & 15;
  const int m0 = mt * 128, n0 = nt * 128;
  f4v acc[4][4] = {};

  for (int ks = 0; ks < KT_DEC; ++ks) {
    const int k0 = ks * 32;
#pragma unroll
    for (int c = 0; c < 2; ++c) {
      int idx = c * 256 + tid;
      size_t abase = (size_t)(mt * 16 + ks) * 4096 + (size_t)idx * 8;
      Ah[idx] = *(const s8v*)(o_hi + abase);
      Al[idx] = *(const s8v*)(o_lo + abase);
      int r = idx >> 2, kg = idx & 3;
      const float* bs = dec_w + (size_t)(n0 + r) * HID + k0 + kg * 8;
      float4 b0 = *(const float4*)bs;
      float4 b1v = *(const float4*)(bs + 4);
      float bv[8] = {b0.x, b0.y, b0.z, b0.w, b1v.x, b1v.y, b1v.z, b1v.w};
      s8v bh, bl;
#pragma unroll
      for (int j = 0; j < 8; ++j) {
        unsigned short h = f2bf_rne(bv[j]);
        bh[j] = (short)h;
        bl[j] = (short)f2bf_rne(bv[j] - bf2f(h));
      }
      int ub = unit_swz(r, kg);
      Bh[ub] = bh;  Bl[ub] = bl;
    }
    __syncthreads();
    s8v afh[4], afl[4], bfh[4], bfl[4];
#pragma unroll
    for (int f = 0; f < 4; ++f) {
      int rA = wm * 64 + f * 16 + lr;
      int uA = unit_swz(rA, kgl);
      afh[f] = Ah[uA];  afl[f] = Al[uA];
      int rB = wn * 64 + f * 16 + lr;
      int uB = unit_swz(rB, kgl);
      bfh[f] = Bh[uB];  bfl[f] = Bl[uB];
    }
#pragma unroll
    for (int i = 0; i < 4; ++i)
#pragma unroll
      for (int j = 0; j < 4; ++j)
        acc[i][j] = MFMA16(afh[i], bfh[j], acc[i][j]);
#pragma unroll
    for (int i = 0; i < 4; ++i)
#pragma unroll
      for (int j = 0; j < 4; ++j)
        acc[i][j] = MFMA16(afl[i], bfh[j], acc[i][j]);
#pragma unroll
    for (int i = 0; i < 4; ++i)
#pragma unroll
      for (int j = 0; j < 4; ++j)
        acc[i][j] = MFMA16(afh[i], bfl[j], acc[i][j]);
    __syncthreads();
  }
#pragma unroll
  for (int j = 0; j < 4; ++j) {
    int col = n0 + wn * 64 + j * 16 + lr;
    float bias = dec_b[col];
#pragma unroll
    for (int i = 0; i < 4; ++i)
#pragma unroll
      for (int rg = 0; rg < 4; ++rg) {
        int row = m0 + wm * 64 + i * 16 + (lane >> 4) * 4 + rg;
        __builtin_nontemporal_store(acc[i][j][rg] + bias,
                                    &out[(size_t)row * VOCAB + col]);
      }
  }
}

// ---------------------------------------------------------------------------
// Workspace layout (bytes):
//   [0,       128 KiB)   hbuf: u64[2][16][512] (tag|f32)   (zeroed each call)
//   [131072]             wq: dec tile queue counter         (zeroed each call)
//   [131136, 132160)     scnt[16] slab counters, 64B apart  (zeroed each call)
//   [2 MiB,    6 MiB)    o_hi: tile-ready A hi images (32x16 tiles x 8 KiB)
//   [6 MiB,   10 MiB)    o_lo: tile-ready A lo images
//   [18 MiB,  26 MiB)    pre : 4096 x 512 f32
//   [26 MiB,  ~57.25M)   bhi : tile-ready dec_w hi
//   [58 MiB,  ~89.25M)   blo : tile-ready dec_w lo
// ---------------------------------------------------------------------------
extern "C" void kernel_launch(void* const* d_in, const int* in_sizes, int n_in,
                              void* d_out, int out_size, void* d_ws, size_t ws_size,
                              hipStream_t stream) {
  (void)in_sizes; (void)n_in; (void)out_size;
  const int*   tok   = (const int*)d_in[0];
  const float* emb   = (const float*)d_in[2];
  const float* w1    = (const float*)d_in[3];
  const float* b1    = (const float*)d_in[4];
  const float* dec_w = (const float*)d_in[5];
  const float* dec_b = (const float*)d_in[6];
  char* ws = (char*)d_ws;
  u64*      hbuf = (u64*)(ws);
  int*      wq   = (int*)(ws + 131072);
  int*      scnt = (int*)(ws + 131136);
  ushort_t* o_hi = (ushort_t*)(ws + (2u << 20));
  ushort_t* o_lo = (ushort_t*)(ws + (6u << 20));
  float*    pre  = (float*)(ws + (18u << 20));
  ushort_t* bhi  = (ushort_t*)(ws + (26u << 20));
  ushort_t* blo  = (ushort_t*)(ws + (58u << 20));
  float* out = (float*)d_out;

  const int big = (ws_size >= (size_t)92 * 1024 * 1024) ? 1 : 0;

  hipMemsetAsync(ws, 0, 132160, stream);   // hbuf + wq + scnt
  head_kernel<<<dim3(4128), dim3(256), 0, stream>>>(
      tok, emb, w1, b1, pre, dec_w, bhi, blo, big);
  hipFuncSetAttribute((const void*)scanodec_kernel,
                      hipFuncAttributeMaxDynamicSharedMemorySize, 131328);
  scanodec_kernel<<<dim3(256), dim3(512), 131328, stream>>>(
      w1, pre, hbuf, o_hi, o_lo, wq, scnt, bhi, blo, dec_b, out,
      out + (size_t)M_TOT * VOCAB, big ? NTILES : 0);
  if (!big)
    dec_gemm_fb<<<dim3(32, 250), dim3(256), 0, stream>>>(o_hi, o_lo, dec_w, dec_b, out);
}